// Round 2
// baseline (14850.594 us; speedup 1.0000x reference)
//
#include <hip/hip_runtime.h>

// CustomRNN: S=2048, B=64, I=256, H=512, E=256.
//   m_t = h_{t-1}@We.T + be ; h_t = tanh([x_t, m_{t-1}]@Wih.T + bih)
// h_t = tanh(x_t@Wx.T + c2 + h_{t-2}@W2), W2 = We.T@Wm.T -> 1024 supersteps.
// 4 groups (16 batch rows) x 2 WGs (256 cols each). Weights in VGPRs.
// Two independent 16-chain halves (A=batch 0-7, B=8-15) staggered per step;
// W2 split local-K/remote-K so the LLC hop hides behind local MFMAs.
// All cross-WG traffic via RELAXED+AGENT atomics (write-through, NO fences).

#define S2    1024
#define OUT_HT 67108864          // 2048*64*512
#define OUT_MT 67141632          // + 64*512

typedef _Float16 half8 __attribute__((ext_vector_type(8)));
typedef float f32x4 __attribute__((ext_vector_type(4)));

#define OFF_W2F   0u         // 512*512 f16 fragment-ordered  (524288)
#define OFF_WXF   524288u    // 512*256 f16 fragment-ordered  (262144)
#define OFF_C2    786432u    // 512 f32   bih + be@Wm.T
#define OFF_AVE   788480u    // 64*512 f32  bih + m0@Wm.T           (t=0)
#define OFF_AVO   919552u    // 64*512 f32  bih + (h0@We.T+be)@Wm.T (t=1)
#define OFF_MEMB  1050624u   // 64*256 f32
#define OFF_HX    1116160u   // [slot2][g4][hf2][w2] x 2048 dwords (262144)
#define OFF_CNT   1378304u   // 8 counters, 64B stride (512)

// ---------------- prep 1: memb = h0@We.T + be ----------------
__global__ __launch_bounds__(256) void k_memb(const float* __restrict__ h0,
                                              const float* __restrict__ We,
                                              const float* __restrict__ be,
                                              float* __restrict__ memb) {
  __shared__ float hs[512];
  int b = blockIdx.x, e = threadIdx.x;
  for (int i = threadIdx.x; i < 512; i += 256) hs[i] = h0[b * 512 + i];
  __syncthreads();
  float acc = be[e];
  const float* wr = We + (size_t)e * 512;
  for (int h = 0; h < 512; ++h) acc += hs[h] * wr[h];
  memb[b * 256 + e] = acc;
}

// ---------------- prep 2: fragments, addvecs, counters ----------------
__global__ __launch_bounds__(256) void k_prep(
    const float* __restrict__ We, const float* __restrict__ be,
    const float* __restrict__ Wih, const float* __restrict__ bih,
    const float* __restrict__ m0, const float* __restrict__ memb,
    _Float16* __restrict__ w2f, _Float16* __restrict__ wxf,
    float* __restrict__ c2, float* __restrict__ ave, float* __restrict__ avo,
    unsigned int* __restrict__ cnt) {
  int blk = blockIdx.x, tid = threadIdx.x;
  if (blk < 1024) {                       // W2[k][n] = sum_e We[e,k]*Wih[n,256+e]
    int idx = blk * 256 + tid;
    int k = idx & 511, n = idx >> 9;
    float acc = 0.f;
    for (int e = 0; e < 256; ++e)
      acc += We[e * 512 + k] * Wih[n * 512 + 256 + e];
    int ntile = n >> 4, nlv = n & 15;
    int kch = k >> 5, kq = (k >> 3) & 3, ke = k & 7;
    int lane = kq * 16 + nlv;
    w2f[(size_t)((ntile * 16 + kch) * 64 + lane) * 8 + ke] = (_Float16)acc;
  } else if (blk < 1536) {                // Wx[k][n] = Wih[n][k], k<256
    int idx = (blk - 1024) * 256 + tid;
    int k = idx & 255, n = idx >> 8;
    float v = Wih[n * 512 + k];
    int ntile = n >> 4, nlv = n & 15;
    int kch = k >> 5, kq = (k >> 3) & 3, ke = k & 7;
    int lane = kq * 16 + nlv;
    wxf[(size_t)((ntile * 8 + kch) * 64 + lane) * 8 + ke] = (_Float16)v;
  } else if (blk < 1538) {                // c2 = bih + be@Wm.T
    int j = (blk - 1536) * 256 + tid;
    float acc = bih[j];
    for (int e = 0; e < 256; ++e) acc += be[e] * Wih[j * 512 + 256 + e];
    c2[j] = acc;
  } else if (blk < 1666) {                // ave = bih + m0@Wm.T
    int i = blk - 1538;
    int b = i >> 1, j = (i & 1) * 256 + tid;
    float acc = bih[j];
    for (int e = 0; e < 256; ++e) acc += m0[b * 256 + e] * Wih[j * 512 + 256 + e];
    ave[b * 512 + j] = acc;
  } else if (blk < 1794) {                // avo = bih + memb@Wm.T
    int i = blk - 1666;
    int b = i >> 1, j = (i & 1) * 256 + tid;
    float acc = bih[j];
    for (int e = 0; e < 256; ++e) acc += memb[b * 256 + e] * Wih[j * 512 + 256 + e];
    avo[b * 512 + j] = acc;
  } else {
    if (tid < 128)
      __hip_atomic_store(&cnt[tid], 0u, __ATOMIC_RELAXED, __HIP_MEMORY_SCOPE_AGENT);
  }
}

// ---------------- main sequential kernel: grid = 8 x 256 ----------------
__global__ __launch_bounds__(256, 1) void k_main(
    const float* __restrict__ x,
    const _Float16* __restrict__ w2f, const _Float16* __restrict__ wxf,
    const float* __restrict__ c2, const float* __restrict__ ave,
    const float* __restrict__ avo, unsigned int* __restrict__ hx,
    unsigned int* __restrict__ cnt, float* __restrict__ out) {
  // stride 260 f16 (520 B): 2-way-max bank aliasing on all access patterns
  __shared__ __align__(16) _Float16 xs[32 * 260];        // x(t=2s, 2s+1)
  __shared__ __align__(16) _Float16 hloc[2][16 * 260];   // own h half [hf][m][jl]
  __shared__ __align__(16) _Float16 hrem[2][16 * 260];   // partner staged

  const int tid = threadIdx.x;
  const int g = blockIdx.x >> 1;         // group 0..3
  const int w = blockIdx.x & 1;          // member: owns cols [w*256, w*256+256)
  const int lane = tid & 63;
  const int wave = tid >> 6;
  const int q = lane >> 4, nl = lane & 15;
  const int nt0 = w * 16 + wave * 4;     // 4 ntiles per wave

  // permanent weight fragments: [i][0..7] local K-chunks, [i][8..15] remote
  half8 w2a[4][16];
  half8 wxr[4][8];
#pragma unroll
  for (int i = 0; i < 4; ++i) {
    int ntile = nt0 + i;
#pragma unroll
    for (int kc = 0; kc < 8; ++kc) {
      int kg_l = w * 8 + kc, kg_r = (1 - w) * 8 + kc;
      w2a[i][kc]     = *(const half8*)(w2f + (size_t)((ntile * 16 + kg_l) * 64 + lane) * 8);
      w2a[i][8 + kc] = *(const half8*)(w2f + (size_t)((ntile * 16 + kg_r) * 64 + lane) * 8);
      wxr[i][kc]     = *(const half8*)(wxf + (size_t)((ntile * 8 + kc) * 64 + lane) * 8);
    }
  }
  float c2l[4];
#pragma unroll
  for (int i = 0; i < 4; ++i) c2l[i] = c2[(nt0 + i) * 16 + nl];

  const int r8 = tid >> 3, seg8 = tid & 7;   // x staging: row, 32-float segment
  const int xb = g * 16 + (r8 & 15);

  // stage x(0): t = parity
  {
    const float* xp = x + ((size_t)((r8 >> 4) * 64 + xb)) * 256 + seg8 * 32;
#pragma unroll
    for (int i = 0; i < 8; ++i) {
      float4 v = *(const float4*)(xp + i * 4);
      union { _Float16 h[4]; short4 sv; } u;
      u.h[0] = (_Float16)v.x; u.h[1] = (_Float16)v.y;
      u.h[2] = (_Float16)v.z; u.h[3] = (_Float16)v.w;
      *(short4*)(&xs[r8 * 260 + seg8 * 32 + i * 4]) = u.sv;
    }
  }
  __syncthreads();

  float4 xv[8];
  for (int s = 0; s < S2; ++s) {
#pragma unroll
    for (int hf = 0; hf < 2; ++hf) {
      if (hf == 1 && s + 1 < S2) {      // prefetch next superstep's x (plain loads)
        const float* xp = x + ((size_t)((2 * s + 2 + (r8 >> 4)) * 64 + xb)) * 256 + seg8 * 32;
#pragma unroll
        for (int i = 0; i < 8; ++i) xv[i] = *(const float4*)(xp + i * 4);
      }
      _Float16* hl = hloc[hf];
      _Float16* hr = hrem[hf];
      unsigned int* cp = cnt + (g * 2 + hf) * 16;
      f32x4 acc[4];
#pragma unroll
      for (int i = 0; i < 4; ++i) acc[i] = (f32x4){0.f, 0.f, 0.f, 0.f};

      if (s > 0) {
        // partner's half-slice for step s-1 must be published (8 wave-publishes/step)
        unsigned int target = 8u * (unsigned int)s;
        while (__hip_atomic_load(cp, __ATOMIC_RELAXED, __HIP_MEMORY_SCOPE_AGENT) < target) {}
        const unsigned int* src =
            hx + (size_t)((((((s - 1) & 1) * 4 + g) * 2 + hf) * 2 + (1 - w)) * 2048);
        unsigned int rv[8];
#pragma unroll
        for (int k = 0; k < 8; ++k)
          rv[k] = __hip_atomic_load(src + tid + k * 256, __ATOMIC_RELAXED,
                                    __HIP_MEMORY_SCOPE_AGENT);
        // local-K W2 (own columns, from LDS) overlaps the LLC loads above
#pragma unroll
        for (int kc = 0; kc < 8; ++kc) {
          half8 a = *(const half8*)(&hl[nl * 260 + kc * 32 + q * 8]);
#pragma unroll
          for (int i = 0; i < 4; ++i)
            acc[i] = __builtin_amdgcn_mfma_f32_16x16x32_f16(a, w2a[i][kc], acc[i], 0, 0, 0);
        }
        unsigned int* dl = (unsigned int*)hr;
#pragma unroll
        for (int k = 0; k < 8; ++k) {
          int d = tid + k * 256;
          dl[(d >> 7) * 130 + (d & 127)] = rv[k];
        }
        __syncthreads();                               // B1: staged data visible
#pragma unroll
        for (int kc = 0; kc < 8; ++kc) {               // remote-K W2
          half8 a = *(const half8*)(&hr[nl * 260 + kc * 32 + q * 8]);
#pragma unroll
          for (int i = 0; i < 4; ++i)
            acc[i] = __builtin_amdgcn_mfma_f32_16x16x32_f16(a, w2a[i][8 + kc], acc[i], 0, 0, 0);
        }
      } else {
        __syncthreads();                               // keep barrier count uniform
      }

      // x contribution
      const int xrow = (nl >> 3) * 16 + hf * 8 + (nl & 7);
#pragma unroll
      for (int kc = 0; kc < 8; ++kc) {
        half8 a = *(const half8*)(&xs[xrow * 260 + kc * 32 + q * 8]);
#pragma unroll
        for (int i = 0; i < 4; ++i)
          acc[i] = __builtin_amdgcn_mfma_f32_16x16x32_f16(a, wxr[i][kc], acc[i], 0, 0, 0);
      }

      // epilogue: bias + tanh, out stores, own-h -> LDS (A-layout for next step)
#pragma unroll
      for (int i = 0; i < 4; ++i) {
        int j = (nt0 + i) * 16 + nl;
        int jl = j - w * 256;
#pragma unroll
        for (int r = 0; r < 4; ++r) {
          int m = q * 4 + r;                           // parity = m>>3, batch = m&7
          int b = g * 16 + hf * 8 + (m & 7);
          float base;
          if (s == 0)
            base = (m < 8) ? ave[(size_t)b * 512 + j] : avo[(size_t)b * 512 + j];
          else
            base = c2l[i];
          float pre = acc[i][r] + base;
          float z = __expf(2.f * pre);
          float h = 1.f - 2.f / (z + 1.f);
          int t = 2 * s + (m >> 3);
          out[(size_t)(t * 64 + b) * 512 + j] = h;
          if (s == S2 - 1 && m >= 8) out[(size_t)OUT_HT + (size_t)b * 512 + j] = h;
          hl[m * 260 + jl] = (_Float16)h;
        }
      }
      __syncthreads();                                 // B2: hl complete

      // publish own slice: LDS -> write-through dword stores -> counter
      {
        unsigned int* dst = hx + (size_t)(((((s & 1) * 4 + g) * 2 + hf) * 2 + w) * 2048);
        const unsigned int* sl = (const unsigned int*)hl;
#pragma unroll
        for (int k = 0; k < 8; ++k) {
          int d = tid + k * 256;
          unsigned int v = sl[(d >> 7) * 130 + (d & 127)];
          __hip_atomic_store(dst + d, v, __ATOMIC_RELAXED, __HIP_MEMORY_SCOPE_AGENT);
        }
        asm volatile("s_waitcnt vmcnt(0)" ::: "memory");
        if (lane == 0)
          __hip_atomic_fetch_add(cp, 1u, __ATOMIC_RELAXED, __HIP_MEMORY_SCOPE_AGENT);
      }
    } // hf

    if (s + 1 < S2) {                                  // convert + stage x(s+1)
#pragma unroll
      for (int i = 0; i < 8; ++i) {
        union { _Float16 h[4]; short4 sv; } u;
        u.h[0] = (_Float16)xv[i].x; u.h[1] = (_Float16)xv[i].y;
        u.h[2] = (_Float16)xv[i].z; u.h[3] = (_Float16)xv[i].w;
        *(short4*)(&xs[r8 * 260 + seg8 * 32 + i * 4]) = u.sv;
      }
    }
  }
}

// ---------------- final m_T = h_2046 @ We.T + be ----------------
__global__ __launch_bounds__(256) void k_mt(float* __restrict__ out,
                                            const float* __restrict__ We,
                                            const float* __restrict__ be) {
  __shared__ float hs[512];
  int b = blockIdx.x, e = threadIdx.x;
  const float* hrow = out + (size_t)(2046 * 64 + b) * 512;
  for (int i = threadIdx.x; i < 512; i += 256) hs[i] = hrow[i];
  __syncthreads();
  float acc = be[e];
  const float* wr = We + (size_t)e * 512;
  for (int h = 0; h < 512; ++h) acc += hs[h] * wr[h];
  out[(size_t)OUT_MT + b * 256 + e] = acc;
}

extern "C" void kernel_launch(void* const* d_in, const int* in_sizes, int n_in,
                              void* d_out, int out_size, void* d_ws, size_t ws_size,
                              hipStream_t stream) {
  const float* x   = (const float*)d_in[0];
  const float* h0  = (const float*)d_in[1];
  const float* m0  = (const float*)d_in[2];
  const float* We  = (const float*)d_in[3];
  const float* be  = (const float*)d_in[4];
  const float* Wih = (const float*)d_in[5];
  const float* bih = (const float*)d_in[6];
  float* out = (float*)d_out;
  char* ws = (char*)d_ws;

  _Float16* w2f = (_Float16*)(ws + OFF_W2F);
  _Float16* wxf = (_Float16*)(ws + OFF_WXF);
  float* c2   = (float*)(ws + OFF_C2);
  float* ave  = (float*)(ws + OFF_AVE);
  float* avo  = (float*)(ws + OFF_AVO);
  float* memb = (float*)(ws + OFF_MEMB);
  unsigned int* hx  = (unsigned int*)(ws + OFF_HX);
  unsigned int* cnt = (unsigned int*)(ws + OFF_CNT);

  k_memb<<<64, 256, 0, stream>>>(h0, We, be, memb);
  k_prep<<<1795, 256, 0, stream>>>(We, be, Wih, bih, m0, memb, w2f, wxf, c2, ave, avo, cnt);
  k_main<<<8, 256, 0, stream>>>(x, w2f, wxf, c2, ave, avo, hx, cnt, out);
  k_mt<<<64, 256, 0, stream>>>(out, We, be);
}